// Round 1
// baseline (1587.598 us; speedup 1.0000x reference)
//
#include <hip/hip_runtime.h>
#include <math.h>

#define NEXP 8
#define TILE 128
#define BK 32
#define LDSW (BK + 8)   // padded row: 40 ushorts = 80B -> 2-way bank aliasing only (free)

typedef __attribute__((ext_vector_type(8))) short short8;
typedef __attribute__((ext_vector_type(4))) float float4v;

__device__ __forceinline__ unsigned short f2bf(float f) {
  union { float f; unsigned u; } v; v.f = f;
  unsigned r = v.u + 0x7FFFu + ((v.u >> 16) & 1u);  // RNE
  return (unsigned short)(r >> 16);
}
__device__ __forceinline__ unsigned pack2(float a, float b) {
  return (unsigned)f2bf(a) | ((unsigned)f2bf(b) << 16);
}

// ---------------- x -> bf16 ----------------
__global__ __launch_bounds__(256) void convert_x_kernel(
    const float* __restrict__ x, unsigned short* __restrict__ xb, int n4) {
  int i = blockIdx.x * 256 + threadIdx.x;
  if (i >= n4) return;
  float4 v = ((const float4*)x)[i];
  uint2 o; o.x = pack2(v.x, v.y); o.y = pack2(v.z, v.w);
  ((uint2*)xb)[i] = o;
}

// ---------------- routing (fp32, selection-exact) ----------------
__global__ __launch_bounds__(256) void routing_kernel(
    const float* __restrict__ x, const float* __restrict__ cw,
    const float* __restrict__ cb, const float* __restrict__ wealth,
    int* __restrict__ plist, int* __restrict__ counts,
    float* __restrict__ w_rt, int T, int H) {
  const int t = blockIdx.x;
  const int tid = threadIdx.x;
  const float* xr = x + (size_t)t * H;
  float acc[NEXP];
#pragma unroll
  for (int e = 0; e < NEXP; ++e) acc[e] = 0.f;
  for (int h = tid; h < H; h += 256) {
    float xv = xr[h];
#pragma unroll
    for (int e = 0; e < NEXP; ++e) acc[e] += xv * cw[e * H + h];
  }
  __shared__ float s[NEXP][256];
#pragma unroll
  for (int e = 0; e < NEXP; ++e) s[e][tid] = acc[e];
  __syncthreads();
  if (tid < NEXP) {
    float v = 0.f;
    for (int j = 0; j < 256; ++j) v += s[tid][j];
    s[tid][0] = v;
  }
  __syncthreads();
  if (tid == 0) {
    float bids[NEXP];
#pragma unroll
    for (int e = 0; e < NEXP; ++e) {
      float lg = s[e][0] + cb[e];
      float c = 1.f / (1.f + expf(-lg));
      bids[e] = c * wealth[e];
    }
    int i0 = 0;
    for (int e = 1; e < NEXP; ++e) if (bids[e] > bids[i0]) i0 = e;  // ties -> lower idx
    int i1 = (i0 == 0) ? 1 : 0;
    for (int e = 0; e < NEXP; ++e) if (e != i0 && bids[e] > bids[i1]) i1 = e;
    float ex = expf(bids[i1] - bids[i0]);
    float wsum = 1.f + ex;
    w_rt[2 * t]     = 1.f / wsum;
    w_rt[2 * t + 1] = ex / wsum;
    int p0 = atomicAdd(&counts[i0], 1);
    plist[i0 * T + p0] = 2 * t;
    int p1 = atomicAdd(&counts[i1], 1);
    plist[i1 * T + p1] = 2 * t + 1;
  }
}

// ---------------- gate+up fused GEMM (gemm_bt), silu epilogue ----------------
// act[p][i] = silu(x_t . gw_e[i]) * (x_t . uw_e[i]),  p = 2t+k
__global__ __launch_bounds__(256) void gateup_kernel(
    const unsigned short* __restrict__ xb, const float* __restrict__ gw,
    const float* __restrict__ uw, const int* __restrict__ plist,
    const int* __restrict__ counts, unsigned short* __restrict__ act,
    int T, int H, int I) {
  const int e = blockIdx.z;
  const int cnt = counts[e];
  const int row0 = blockIdx.x * TILE;   // x = token-tile (fast) -> weight reuse in L2
  if (row0 >= cnt) return;
  const int i0 = blockIdx.y * TILE;

  __shared__ __align__(16) unsigned short As[TILE][LDSW];
  __shared__ __align__(16) unsigned short Bg[TILE][LDSW];
  __shared__ __align__(16) unsigned short Bu[TILE][LDSW];

  const int tid = threadIdx.x;
  const int lane = tid & 63;
  const int wv = tid >> 6;
  const int wm = wv >> 1, wn = wv & 1;
  const int quad = lane >> 4, l15 = lane & 15;

  float4v accg[4][4], accu[4][4];
#pragma unroll
  for (int a = 0; a < 4; ++a)
#pragma unroll
    for (int b = 0; b < 4; ++b) {
      float4v z = {0.f, 0.f, 0.f, 0.f};
      accg[a][b] = z; accu[a][b] = z;
    }

  const int ar = tid >> 1;
  const int acol = (tid & 1) * 16;  // 16 bf16 per thread per K-step
  int pa = (row0 + ar < cnt) ? plist[e * T + row0 + ar] : 0;
  const unsigned short* aptr = xb + (size_t)(pa >> 1) * H + acol;

  const int br = tid >> 1;
  const int bcol = (tid & 1) * 16;  // 16 floats per thread per K-step
  const float* gptr = gw + ((size_t)e * I + i0 + br) * H + bcol;
  const float* uptr = uw + ((size_t)e * I + i0 + br) * H + bcol;

  for (int k0 = 0; k0 < H; k0 += BK) {
    __syncthreads();
    {
      uint4 v0 = ((const uint4*)(aptr + k0))[0];
      uint4 v1 = ((const uint4*)(aptr + k0))[1];
      *(uint4*)&As[ar][acol] = v0;
      *(uint4*)&As[ar][acol + 8] = v1;
    }
    {
      const float4* sg = (const float4*)(gptr + k0);
      float4 v0 = sg[0], v1 = sg[1], v2 = sg[2], v3 = sg[3];
      uint4 o0, o1;
      o0.x = pack2(v0.x, v0.y); o0.y = pack2(v0.z, v0.w);
      o0.z = pack2(v1.x, v1.y); o0.w = pack2(v1.z, v1.w);
      o1.x = pack2(v2.x, v2.y); o1.y = pack2(v2.z, v2.w);
      o1.z = pack2(v3.x, v3.y); o1.w = pack2(v3.z, v3.w);
      *(uint4*)&Bg[br][bcol] = o0;
      *(uint4*)&Bg[br][bcol + 8] = o1;
    }
    {
      const float4* su = (const float4*)(uptr + k0);
      float4 v0 = su[0], v1 = su[1], v2 = su[2], v3 = su[3];
      uint4 o0, o1;
      o0.x = pack2(v0.x, v0.y); o0.y = pack2(v0.z, v0.w);
      o0.z = pack2(v1.x, v1.y); o0.w = pack2(v1.z, v1.w);
      o1.x = pack2(v2.x, v2.y); o1.y = pack2(v2.z, v2.w);
      o1.z = pack2(v3.x, v3.y); o1.w = pack2(v3.z, v3.w);
      *(uint4*)&Bu[br][bcol] = o0;
      *(uint4*)&Bu[br][bcol + 8] = o1;
    }
    __syncthreads();
    short8 af[4], bg[4], bu[4];
#pragma unroll
    for (int mi = 0; mi < 4; ++mi)
      af[mi] = *(const short8*)&As[wm * 64 + mi * 16 + l15][quad * 8];
#pragma unroll
    for (int ni = 0; ni < 4; ++ni) {
      bg[ni] = *(const short8*)&Bg[wn * 64 + ni * 16 + l15][quad * 8];
      bu[ni] = *(const short8*)&Bu[wn * 64 + ni * 16 + l15][quad * 8];
    }
#pragma unroll
    for (int mi = 0; mi < 4; ++mi)
#pragma unroll
      for (int ni = 0; ni < 4; ++ni) {
        accg[mi][ni] = __builtin_amdgcn_mfma_f32_16x16x32_bf16(af[mi], bg[ni], accg[mi][ni], 0, 0, 0);
        accu[mi][ni] = __builtin_amdgcn_mfma_f32_16x16x32_bf16(af[mi], bu[ni], accu[mi][ni], 0, 0, 0);
      }
  }

  // epilogue: C/D layout col=lane&15, row=quad*4+reg (verified m89/m91)
#pragma unroll
  for (int mi = 0; mi < 4; ++mi) {
    int rbase = wm * 64 + mi * 16 + quad * 4;
#pragma unroll
    for (int r = 0; r < 4; ++r) {
      int grow = row0 + rbase + r;
      if (grow < cnt) {
        int p = plist[e * T + grow];
        size_t base = (size_t)p * I + i0 + wn * 64 + l15;
#pragma unroll
        for (int ni = 0; ni < 4; ++ni) {
          float g = accg[mi][ni][r];
          float u = accu[mi][ni][r];
          float s = g / (1.f + __expf(-g)) * u;  // silu(g)*u
          act[base + ni * 16] = f2bf(s);
        }
      }
    }
  }
}

// ---------------- down GEMM: part[p][h] = act[p] . dw_e[h] ----------------
__global__ __launch_bounds__(256) void down_kernel(
    const unsigned short* __restrict__ act, const float* __restrict__ dw,
    const int* __restrict__ plist, const int* __restrict__ counts,
    float* __restrict__ part, int T, int H, int I) {
  const int e = blockIdx.z;
  const int cnt = counts[e];
  const int row0 = blockIdx.x * TILE;
  if (row0 >= cnt) return;
  const int h0 = blockIdx.y * TILE;

  __shared__ __align__(16) unsigned short As[TILE][LDSW];
  __shared__ __align__(16) unsigned short Bs[TILE][LDSW];

  const int tid = threadIdx.x;
  const int lane = tid & 63;
  const int wv = tid >> 6;
  const int wm = wv >> 1, wn = wv & 1;
  const int quad = lane >> 4, l15 = lane & 15;

  float4v acc[4][4];
#pragma unroll
  for (int a = 0; a < 4; ++a)
#pragma unroll
    for (int b = 0; b < 4; ++b) { float4v z = {0.f, 0.f, 0.f, 0.f}; acc[a][b] = z; }

  const int ar = tid >> 1;
  const int acol = (tid & 1) * 16;
  int pa = (row0 + ar < cnt) ? plist[e * T + row0 + ar] : 0;
  const unsigned short* aptr = act + (size_t)pa * I + acol;

  const int br = tid >> 1;
  const int bcol = (tid & 1) * 16;
  const float* bptr = dw + ((size_t)e * H + h0 + br) * I + bcol;

  for (int k0 = 0; k0 < I; k0 += BK) {
    __syncthreads();
    {
      uint4 v0 = ((const uint4*)(aptr + k0))[0];
      uint4 v1 = ((const uint4*)(aptr + k0))[1];
      *(uint4*)&As[ar][acol] = v0;
      *(uint4*)&As[ar][acol + 8] = v1;
    }
    {
      const float4* sb = (const float4*)(bptr + k0);
      float4 v0 = sb[0], v1 = sb[1], v2 = sb[2], v3 = sb[3];
      uint4 o0, o1;
      o0.x = pack2(v0.x, v0.y); o0.y = pack2(v0.z, v0.w);
      o0.z = pack2(v1.x, v1.y); o0.w = pack2(v1.z, v1.w);
      o1.x = pack2(v2.x, v2.y); o1.y = pack2(v2.z, v2.w);
      o1.z = pack2(v3.x, v3.y); o1.w = pack2(v3.z, v3.w);
      *(uint4*)&Bs[br][bcol] = o0;
      *(uint4*)&Bs[br][bcol + 8] = o1;
    }
    __syncthreads();
    short8 af[4], bf[4];
#pragma unroll
    for (int mi = 0; mi < 4; ++mi)
      af[mi] = *(const short8*)&As[wm * 64 + mi * 16 + l15][quad * 8];
#pragma unroll
    for (int ni = 0; ni < 4; ++ni)
      bf[ni] = *(const short8*)&Bs[wn * 64 + ni * 16 + l15][quad * 8];
#pragma unroll
    for (int mi = 0; mi < 4; ++mi)
#pragma unroll
      for (int ni = 0; ni < 4; ++ni)
        acc[mi][ni] = __builtin_amdgcn_mfma_f32_16x16x32_bf16(af[mi], bf[ni], acc[mi][ni], 0, 0, 0);
  }

#pragma unroll
  for (int mi = 0; mi < 4; ++mi) {
    int rbase = wm * 64 + mi * 16 + quad * 4;
#pragma unroll
    for (int r = 0; r < 4; ++r) {
      int grow = row0 + rbase + r;
      if (grow < cnt) {
        int p = plist[e * T + grow];
        size_t base = (size_t)p * H + h0 + wn * 64 + l15;
#pragma unroll
        for (int ni = 0; ni < 4; ++ni)
          part[base + ni * 16] = acc[mi][ni][r];
      }
    }
  }
}

// ---------------- combine: out = w0*part[2t] + w1*part[2t+1] ----------------
__global__ __launch_bounds__(256) void combine_kernel(
    const float* __restrict__ part, const float* __restrict__ w_rt,
    float* __restrict__ out, int T, int H) {
  int h4 = H >> 2;
  int n4 = T * h4;
  int i = blockIdx.x * 256 + threadIdx.x;
  if (i >= n4) return;
  int t = i / h4;
  int c = i - t * h4;
  float w0 = w_rt[2 * t], w1 = w_rt[2 * t + 1];
  float4 a = ((const float4*)(part + (size_t)(2 * t) * H))[c];
  float4 b = ((const float4*)(part + (size_t)(2 * t + 1) * H))[c];
  float4 o;
  o.x = w0 * a.x + w1 * b.x;
  o.y = w0 * a.y + w1 * b.y;
  o.z = w0 * a.z + w1 * b.z;
  o.w = w0 * a.w + w1 * b.w;
  ((float4*)(out + (size_t)t * H))[c] = o;
}

extern "C" void kernel_launch(void* const* d_in, const int* in_sizes, int n_in,
                              void* d_out, int out_size, void* d_ws, size_t ws_size,
                              hipStream_t stream) {
  const float* x      = (const float*)d_in[0];
  const float* cw     = (const float*)d_in[1];
  const float* cb     = (const float*)d_in[2];
  const float* gw     = (const float*)d_in[3];
  const float* uw     = (const float*)d_in[4];
  const float* dw     = (const float*)d_in[5];
  const float* wealth = (const float*)d_in[6];
  float* out = (float*)d_out;

  const int H = in_sizes[1] / NEXP;          // conf_w (E,H)
  const int T = in_sizes[0] / H;             // hidden (B*S,H)
  const int I = in_sizes[3] / (NEXP * H);    // gate_w (E,I,H)

  char* ws = (char*)d_ws;
  size_t off = 0;
  unsigned short* xb = (unsigned short*)(ws + off); off += (size_t)T * H * 2;
  unsigned short* act = (unsigned short*)(ws + off); off += (size_t)2 * T * I * 2;
  float* part = (float*)(ws + off); off += (size_t)2 * T * H * 4;
  int* plist = (int*)(ws + off); off += (size_t)NEXP * T * 4;
  float* w_rt = (float*)(ws + off); off += (size_t)T * 2 * 4;
  int* counts = (int*)(ws + off); off += NEXP * 4;

  hipMemsetAsync(counts, 0, NEXP * sizeof(int), stream);

  int n4 = (T * H) / 4;
  convert_x_kernel<<<(n4 + 255) / 256, 256, 0, stream>>>(x, xb, n4);
  routing_kernel<<<T, 256, 0, stream>>>(x, cw, cb, wealth, plist, counts, w_rt, T, H);

  int ttiles = (T + TILE - 1) / TILE;
  dim3 g1(ttiles, I / TILE, NEXP);
  gateup_kernel<<<g1, 256, 0, stream>>>(xb, gw, uw, plist, counts, act, T, H, I);

  dim3 g2(ttiles, H / TILE, NEXP);
  down_kernel<<<g2, 256, 0, stream>>>(act, dw, plist, counts, part, T, H, I);

  combine_kernel<<<(n4 + 255) / 256, 256, 0, stream>>>(part, w_rt, out, T, H);
}

// Round 2
// 949.039 us; speedup vs baseline: 1.6728x; 1.6728x over previous
//
#include <hip/hip_runtime.h>
#include <math.h>

#define NEXP 8
#define TILE 128
#define BK 32

typedef __attribute__((ext_vector_type(8))) short short8;
typedef __attribute__((ext_vector_type(4))) float float4v;

__device__ __forceinline__ unsigned short f2bf(float f) {
  union { float f; unsigned u; } v; v.f = f;
  unsigned r = v.u + 0x7FFFu + ((v.u >> 16) & 1u);  // RNE
  return (unsigned short)(r >> 16);
}
__device__ __forceinline__ unsigned pack2(float a, float b) {
  return (unsigned)f2bf(a) | ((unsigned)f2bf(b) << 16);
}

// async global->LDS, 16B per lane. LDS dst is wave-uniform base + lane*16.
// addrspace casts done via integer round-trip (generic LDS ptr low 32 bits = LDS offset).
__device__ __forceinline__ void gll16(const void* g, void* l) {
  __builtin_amdgcn_global_load_lds(
      (const __attribute__((address_space(1))) unsigned int*)(unsigned long long)(uintptr_t)g,
      (__attribute__((address_space(3))) unsigned int*)(unsigned)(uintptr_t)l,
      16, 0, 0);
}

// ---------------- x -> bf16 (row-major, for gathered A loads) ----------------
__global__ __launch_bounds__(256) void convert_x_kernel(
    const float* __restrict__ x, unsigned short* __restrict__ xb, int n4) {
  int i = blockIdx.x * 256 + threadIdx.x;
  if (i >= n4) return;
  float4 v = ((const float4*)x)[i];
  uint2 o; o.x = pack2(v.x, v.y); o.y = pack2(v.z, v.w);
  ((uint2*)xb)[i] = o;
}

// ---------------- pack fp32 weights -> bf16 GEMM panels ----------------
// src: [E][R][K] fp32 row-major (R = gridDim.y*TILE rows/expert)
// dst: [E][rt][ks] panels of [128 rows][32 cols] bf16, panel = 8KB contiguous
// grid: (K/BK, R/TILE, E), block 256: tid -> r = tid>>1, half = tid&1 (16 cols each)
__global__ __launch_bounds__(256) void pack_w_kernel(
    const float* __restrict__ src, unsigned short* __restrict__ dst, int K) {
  const int ks = blockIdx.x, rt = blockIdx.y, e = blockIdx.z;
  const int n_ks = gridDim.x, n_rt = gridDim.y;
  const int r = threadIdx.x >> 1, half = threadIdx.x & 1;
  const size_t R = (size_t)n_rt * TILE;
  const float4* s = (const float4*)(src + ((size_t)e * R + rt * TILE + r) * K + ks * BK + half * 16);
  float4 v0 = s[0], v1 = s[1], v2 = s[2], v3 = s[3];
  uint4 o0, o1;
  o0.x = pack2(v0.x, v0.y); o0.y = pack2(v0.z, v0.w);
  o0.z = pack2(v1.x, v1.y); o0.w = pack2(v1.z, v1.w);
  o1.x = pack2(v2.x, v2.y); o1.y = pack2(v2.z, v2.w);
  o1.z = pack2(v3.x, v3.y); o1.w = pack2(v3.z, v3.w);
  unsigned short* d = dst + ((size_t)(e * n_rt + rt) * n_ks + ks) * (TILE * BK)
                          + r * BK + half * 16;
  *(uint4*)d = o0;
  *(uint4*)(d + 8) = o1;
}

// ---------------- routing (fp32, selection-exact) ----------------
__global__ __launch_bounds__(256) void routing_kernel(
    const float* __restrict__ x, const float* __restrict__ cw,
    const float* __restrict__ cb, const float* __restrict__ wealth,
    int* __restrict__ plist, int* __restrict__ counts,
    float* __restrict__ w_rt, int T, int H) {
  const int t = blockIdx.x;
  const int tid = threadIdx.x;
  const float* xr = x + (size_t)t * H;
  float acc[NEXP];
#pragma unroll
  for (int e = 0; e < NEXP; ++e) acc[e] = 0.f;
  for (int h = tid; h < H; h += 256) {
    float xv = xr[h];
#pragma unroll
    for (int e = 0; e < NEXP; ++e) acc[e] += xv * cw[e * H + h];
  }
  __shared__ float s[NEXP][256];
#pragma unroll
  for (int e = 0; e < NEXP; ++e) s[e][tid] = acc[e];
  __syncthreads();
  for (int st = 128; st > 0; st >>= 1) {
    if (tid < st) {
#pragma unroll
      for (int e = 0; e < NEXP; ++e) s[e][tid] += s[e][tid + st];
    }
    __syncthreads();
  }
  if (tid == 0) {
    float bids[NEXP];
#pragma unroll
    for (int e = 0; e < NEXP; ++e) {
      float lg = s[e][0] + cb[e];
      float c = 1.f / (1.f + expf(-lg));
      bids[e] = c * wealth[e];
    }
    int i0 = 0;
    for (int e = 1; e < NEXP; ++e) if (bids[e] > bids[i0]) i0 = e;  // ties -> lower idx
    int i1 = (i0 == 0) ? 1 : 0;
    for (int e = 0; e < NEXP; ++e) if (e != i0 && bids[e] > bids[i1]) i1 = e;
    float ex = expf(bids[i1] - bids[i0]);
    float wsum = 1.f + ex;
    w_rt[2 * t]     = 1.f / wsum;
    w_rt[2 * t + 1] = ex / wsum;
    int p0 = atomicAdd(&counts[i0], 1);
    plist[i0 * T + p0] = 2 * t;
    int p1 = atomicAdd(&counts[i1], 1);
    plist[i1 * T + p1] = 2 * t + 1;
  }
}

// ---------------- gate+up fused GEMM, m97 structure, silu epilogue ----------------
__global__ __launch_bounds__(256, 2) void gateup_kernel(
    const unsigned short* __restrict__ xb, const unsigned short* __restrict__ gwp,
    const unsigned short* __restrict__ uwp, const int* __restrict__ plist,
    const int* __restrict__ counts, unsigned short* __restrict__ act,
    int T, int H, int I) {
  const int e = blockIdx.z;
  const int cnt = counts[e];
  const int row0 = blockIdx.x * TILE;
  if (row0 >= cnt) return;
  const int it = blockIdx.y;
  const int nks = H / BK;  // 32

  __shared__ __align__(16) unsigned short As[TILE * BK];
  __shared__ __align__(16) unsigned short Bg[TILE * BK];
  __shared__ __align__(16) unsigned short Bu[TILE * BK];

  const int tid = threadIdx.x, lane = tid & 63, wv = tid >> 6;
  const int wm = wv >> 1, wn = wv & 1;
  const int quad = lane >> 4, l15 = lane & 15;

  // A gather: wave wv stages LDS chunks c0=wv*2, c1=wv*2+1 (16 rows each)
  int ri0 = row0 + wv * 32 + (lane >> 2);
  int ri1 = ri0 + 16;
  if (ri0 >= cnt) ri0 = cnt - 1;
  if (ri1 >= cnt) ri1 = cnt - 1;
  const unsigned short* a0 = xb + (size_t)(plist[e * T + ri0] >> 1) * H + (lane & 3) * 8;
  const unsigned short* a1 = xb + (size_t)(plist[e * T + ri1] >> 1) * H + (lane & 3) * 8;

  const size_t pan = ((size_t)(e * gridDim.y + it) * nks) * (TILE * BK);
  const unsigned short* g0 = gwp + pan + (size_t)wv * 1024 + lane * 8;
  const unsigned short* g1 = g0 + 512;
  const unsigned short* u0 = uwp + pan + (size_t)wv * 1024 + lane * 8;
  const unsigned short* u1 = u0 + 512;

  unsigned short* lA0 = As + wv * 1024; unsigned short* lA1 = lA0 + 512;
  unsigned short* lG0 = Bg + wv * 1024; unsigned short* lG1 = lG0 + 512;
  unsigned short* lU0 = Bu + wv * 1024; unsigned short* lU1 = lU0 + 512;

  float4v accg[4][4], accu[4][4];
#pragma unroll
  for (int a = 0; a < 4; ++a)
#pragma unroll
    for (int b = 0; b < 4; ++b) {
      float4v z = {0.f, 0.f, 0.f, 0.f};
      accg[a][b] = z; accu[a][b] = z;
    }

  for (int k = 0; k < nks; ++k) {
    __syncthreads();
    gll16(a0, lA0); gll16(a1, lA1);
    gll16(g0, lG0); gll16(g1, lG1);
    gll16(u0, lU0); gll16(u1, lU1);
    a0 += BK; a1 += BK;
    g0 += TILE * BK; g1 += TILE * BK;
    u0 += TILE * BK; u1 += TILE * BK;
    __syncthreads();
    short8 af[4], bg[4], bu[4];
#pragma unroll
    for (int mi = 0; mi < 4; ++mi)
      af[mi] = *(const short8*)(As + (wm * 64 + mi * 16 + l15) * BK + quad * 8);
#pragma unroll
    for (int ni = 0; ni < 4; ++ni) {
      bg[ni] = *(const short8*)(Bg + (wn * 64 + ni * 16 + l15) * BK + quad * 8);
      bu[ni] = *(const short8*)(Bu + (wn * 64 + ni * 16 + l15) * BK + quad * 8);
    }
#pragma unroll
    for (int mi = 0; mi < 4; ++mi)
#pragma unroll
      for (int ni = 0; ni < 4; ++ni) {
        accg[mi][ni] = __builtin_amdgcn_mfma_f32_16x16x32_bf16(af[mi], bg[ni], accg[mi][ni], 0, 0, 0);
        accu[mi][ni] = __builtin_amdgcn_mfma_f32_16x16x32_bf16(af[mi], bu[ni], accu[mi][ni], 0, 0, 0);
      }
  }

  // epilogue: C/D layout col=lane&15, row=quad*4+reg
#pragma unroll
  for (int mi = 0; mi < 4; ++mi) {
    int rbase = wm * 64 + mi * 16 + quad * 4;
#pragma unroll
    for (int r = 0; r < 4; ++r) {
      int grow = row0 + rbase + r;
      if (grow < cnt) {
        int p = plist[e * T + grow];
        size_t base = (size_t)p * I + it * TILE + wn * 64 + l15;
#pragma unroll
        for (int ni = 0; ni < 4; ++ni) {
          float g = accg[mi][ni][r];
          float u = accu[mi][ni][r];
          float s = g / (1.f + __expf(-g)) * u;  // silu(g)*u
          act[base + ni * 16] = f2bf(s);
        }
      }
    }
  }
}

// ---------------- down GEMM, m97 structure, split-K=2 ----------------
__global__ __launch_bounds__(256, 2) void down_kernel(
    const unsigned short* __restrict__ act, const unsigned short* __restrict__ dwp,
    const int* __restrict__ plist, const int* __restrict__ counts,
    float* __restrict__ part, int T, int H, int I) {
  const int zz = blockIdx.z;
  const int e = zz >> 1, split = zz & 1;
  const int cnt = counts[e];
  const int row0 = blockIdx.x * TILE;
  if (row0 >= cnt) return;
  const int ht = blockIdx.y;
  const int nks_tot = I / BK;      // 128
  const int nks = nks_tot >> 1;    // 64 per split
  const int k0 = split * nks;

  __shared__ __align__(16) unsigned short As[TILE * BK];
  __shared__ __align__(16) unsigned short Bs[TILE * BK];

  const int tid = threadIdx.x, lane = tid & 63, wv = tid >> 6;
  const int wm = wv >> 1, wn = wv & 1;
  const int quad = lane >> 4, l15 = lane & 15;

  int ri0 = row0 + wv * 32 + (lane >> 2);
  int ri1 = ri0 + 16;
  if (ri0 >= cnt) ri0 = cnt - 1;
  if (ri1 >= cnt) ri1 = cnt - 1;
  const unsigned short* a0 = act + (size_t)plist[e * T + ri0] * I + k0 * BK + (lane & 3) * 8;
  const unsigned short* a1 = act + (size_t)plist[e * T + ri1] * I + k0 * BK + (lane & 3) * 8;

  const size_t pan = ((size_t)(e * gridDim.y + ht) * nks_tot + k0) * (TILE * BK);
  const unsigned short* b0 = dwp + pan + (size_t)wv * 1024 + lane * 8;
  const unsigned short* b1 = b0 + 512;

  unsigned short* lA0 = As + wv * 1024; unsigned short* lA1 = lA0 + 512;
  unsigned short* lB0 = Bs + wv * 1024; unsigned short* lB1 = lB0 + 512;

  float4v acc[4][4];
#pragma unroll
  for (int a = 0; a < 4; ++a)
#pragma unroll
    for (int b = 0; b < 4; ++b) { float4v z = {0.f, 0.f, 0.f, 0.f}; acc[a][b] = z; }

  for (int k = 0; k < nks; ++k) {
    __syncthreads();
    gll16(a0, lA0); gll16(a1, lA1);
    gll16(b0, lB0); gll16(b1, lB1);
    a0 += BK; a1 += BK;
    b0 += TILE * BK; b1 += TILE * BK;
    __syncthreads();
    short8 af[4], bf[4];
#pragma unroll
    for (int mi = 0; mi < 4; ++mi)
      af[mi] = *(const short8*)(As + (wm * 64 + mi * 16 + l15) * BK + quad * 8);
#pragma unroll
    for (int ni = 0; ni < 4; ++ni)
      bf[ni] = *(const short8*)(Bs + (wn * 64 + ni * 16 + l15) * BK + quad * 8);
#pragma unroll
    for (int mi = 0; mi < 4; ++mi)
#pragma unroll
      for (int ni = 0; ni < 4; ++ni)
        acc[mi][ni] = __builtin_amdgcn_mfma_f32_16x16x32_bf16(af[mi], bf[ni], acc[mi][ni], 0, 0, 0);
  }

#pragma unroll
  for (int mi = 0; mi < 4; ++mi) {
    int rbase = wm * 64 + mi * 16 + quad * 4;
#pragma unroll
    for (int r = 0; r < 4; ++r) {
      int grow = row0 + rbase + r;
      if (grow < cnt) {
        int p = plist[e * T + grow];
        size_t base = ((size_t)split * 2 * T + p) * H + ht * TILE + wn * 64 + l15;
#pragma unroll
        for (int ni = 0; ni < 4; ++ni)
          part[base + ni * 16] = acc[mi][ni][r];
      }
    }
  }
}

// ---------------- combine: out = w0*(p00+p10) + w1*(p01+p11) ----------------
__global__ __launch_bounds__(256) void combine_kernel(
    const float* __restrict__ part, const float* __restrict__ w_rt,
    float* __restrict__ out, int T, int H) {
  int h4 = H >> 2;
  int n4 = T * h4;
  int i = blockIdx.x * 256 + threadIdx.x;
  if (i >= n4) return;
  int t = i / h4;
  int c = i - t * h4;
  float w0 = w_rt[2 * t], w1 = w_rt[2 * t + 1];
  size_t splitoff = (size_t)2 * T * H / 4;  // in float4 units: 2T*H floats / 4
  const float4* pa = (const float4*)(part + (size_t)(2 * t) * H);
  const float4* pb = (const float4*)(part + (size_t)(2 * t + 1) * H);
  float4 a0 = pa[c], a1 = pa[c + splitoff];
  float4 b0 = pb[c], b1 = pb[c + splitoff];
  float4 o;
  o.x = w0 * (a0.x + a1.x) + w1 * (b0.x + b1.x);
  o.y = w0 * (a0.y + a1.y) + w1 * (b0.y + b1.y);
  o.z = w0 * (a0.z + a1.z) + w1 * (b0.z + b1.z);
  o.w = w0 * (a0.w + a1.w) + w1 * (b0.w + b1.w);
  ((float4*)(out + (size_t)t * H))[c] = o;
}

extern "C" void kernel_launch(void* const* d_in, const int* in_sizes, int n_in,
                              void* d_out, int out_size, void* d_ws, size_t ws_size,
                              hipStream_t stream) {
  const float* x      = (const float*)d_in[0];
  const float* cw     = (const float*)d_in[1];
  const float* cb     = (const float*)d_in[2];
  const float* gw     = (const float*)d_in[3];
  const float* uw     = (const float*)d_in[4];
  const float* dw     = (const float*)d_in[5];
  const float* wealth = (const float*)d_in[6];
  float* out = (float*)d_out;

  const int H = in_sizes[1] / NEXP;          // conf_w (E,H)
  const int T = in_sizes[0] / H;             // hidden (B*S,H)
  const int I = in_sizes[3] / (NEXP * H);    // gate_w (E,I,H)

  char* ws = (char*)d_ws;
  size_t off = 0;
  unsigned short* xb  = (unsigned short*)(ws + off); off += (size_t)T * H * 2;
  unsigned short* act = (unsigned short*)(ws + off); off += (size_t)2 * T * I * 2;
  float* part = (float*)(ws + off); off += (size_t)2 * 2 * T * H * 4;  // split-K=2
  unsigned short* gwp = (unsigned short*)(ws + off); off += (size_t)NEXP * I * H * 2;
  unsigned short* uwp = (unsigned short*)(ws + off); off += (size_t)NEXP * I * H * 2;
  unsigned short* dwp = gwp;  // reuse: dw pack launched after gateup completes (same stream)
  int* plist = (int*)(ws + off); off += (size_t)NEXP * T * 4;
  float* w_rt = (float*)(ws + off); off += (size_t)T * 2 * 4;
  int* counts = (int*)(ws + off); off += NEXP * 4;

  hipMemsetAsync(counts, 0, NEXP * sizeof(int), stream);

  int n4 = (T * H) / 4;
  convert_x_kernel<<<(n4 + 255) / 256, 256, 0, stream>>>(x, xb, n4);
  routing_kernel<<<T, 256, 0, stream>>>(x, cw, cb, wealth, plist, counts, w_rt, T, H);

  dim3 gp(H / BK, I / TILE, NEXP);
  pack_w_kernel<<<gp, 256, 0, stream>>>(gw, gwp, H);
  pack_w_kernel<<<gp, 256, 0, stream>>>(uw, uwp, H);

  int ttiles = (T + TILE - 1) / TILE;
  dim3 g1(ttiles, I / TILE, NEXP);
  gateup_kernel<<<g1, 256, 0, stream>>>(xb, gwp, uwp, plist, counts, act, T, H, I);

  dim3 gpd(I / BK, H / TILE, NEXP);
  pack_w_kernel<<<gpd, 256, 0, stream>>>(dw, dwp, I);

  dim3 g2(ttiles, H / TILE, NEXP * 2);  // z = expert*2 + ksplit
  down_kernel<<<g2, 256, 0, stream>>>(act, dwp, plist, counts, part, T, H, I);

  combine_kernel<<<(n4 + 255) / 256, 256, 0, stream>>>(part, w_rt, out, T, H);
}